// Round 10
// baseline (429.913 us; speedup 1.0000x reference)
//
#include <hip/hip_runtime.h>
#include <cfloat>

#define KC 512        // codes
#define DD 64         // dim
#define HW 4096       // 64*64
#define NPIX 131072   // 32*64*64
#define QSIZE 8388608 // 32*64*64*64
#define PXB 64        // pixels per block
#define NBLK (NPIX / PXB)  // 2048
#define NTH 256       // 4 waves
#define MARGIN 4.0e-3f  // >6x worst-case screen-vs-np error bound

typedef short short8 __attribute__((ext_vector_type(8)));   // 8 bf16 MFMA operand
typedef float f32x4 __attribute__((ext_vector_type(4)));
typedef float nfloat4 __attribute__((ext_vector_type(4)));
typedef unsigned long long u64;

__device__ __forceinline__ unsigned short bf16_rne(float f) {
    unsigned int u = __float_as_uint(f);
    u += 0x7FFFu + ((u >> 16) & 1u);
    return (unsigned short)(u >> 16);
}

// --- prep (once per launch): swizzled bf16 B-frag codebook (64 KB) + np w2.
// Slot s=(ct*2+kc)*64+ln holds w[ct*16+(ln&15)][kc*32+(ln>>4)*8 .. +8) as bf16.
__global__ __launch_bounds__(1024) void prep(
    const float* __restrict__ w, float* __restrict__ w2g,
    uint4* __restrict__ wswz) {
  const int gt = blockIdx.x * 1024 + threadIdx.x;   // 0..4095
  {
    int ct = gt >> 7, kc = (gt >> 6) & 1, ln = gt & 63;
    int n = ln & 15, q = ln >> 4;
    const float* wp = w + (ct * 16 + n) * DD + kc * 32 + q * 8;
    nfloat4 f0 = *(const nfloat4*)(wp);
    nfloat4 f1 = *(const nfloat4*)(wp + 4);
    uint4 u;
    u.x = (unsigned)bf16_rne(f0[0]) | ((unsigned)bf16_rne(f0[1]) << 16);
    u.y = (unsigned)bf16_rne(f0[2]) | ((unsigned)bf16_rne(f0[3]) << 16);
    u.z = (unsigned)bf16_rne(f1[0]) | ((unsigned)bf16_rne(f1[1]) << 16);
    u.w = (unsigned)bf16_rne(f1[2]) | ((unsigned)bf16_rne(f1[3]) << 16);
    wswz[gt] = u;
  }
  if (gt < KC) {      // w2g[k]: numpy-pairwise fp32 sum of squares
    const float* wk = w + gt * DD;
    float r0 = __fmul_rn(wk[0], wk[0]), r1 = __fmul_rn(wk[1], wk[1]),
          r2 = __fmul_rn(wk[2], wk[2]), r3 = __fmul_rn(wk[3], wk[3]),
          r4 = __fmul_rn(wk[4], wk[4]), r5 = __fmul_rn(wk[5], wk[5]),
          r6 = __fmul_rn(wk[6], wk[6]), r7 = __fmul_rn(wk[7], wk[7]);
    #pragma unroll
    for (int i = 8; i < DD; i += 8) {
      r0 = __fadd_rn(r0, __fmul_rn(wk[i+0], wk[i+0]));
      r1 = __fadd_rn(r1, __fmul_rn(wk[i+1], wk[i+1]));
      r2 = __fadd_rn(r2, __fmul_rn(wk[i+2], wk[i+2]));
      r3 = __fadd_rn(r3, __fmul_rn(wk[i+3], wk[i+3]));
      r4 = __fadd_rn(r4, __fmul_rn(wk[i+4], wk[i+4]));
      r5 = __fadd_rn(r5, __fmul_rn(wk[i+5], wk[i+5]));
      r6 = __fadd_rn(r6, __fmul_rn(wk[i+6], wk[i+6]));
      r7 = __fadd_rn(r7, __fmul_rn(wk[i+7], wk[i+7]));
    }
    w2g[gt] = __fadd_rn(__fadd_rn(__fadd_rn(r0, r1), __fadd_rn(r2, r3)),
                        __fadd_rn(__fadd_rn(r4, r5), __fadd_rn(r6, r7)));
  }
}

// --- main: 64 px/block, ~7 KB LDS -> up to 6 blocks/CU. B-frags read
// directly from the prep-built global array (coalesced dwordx4, L1/L2-hot).
// Precision path identical to R9 (passed): bf16-MFMA screen + MARGIN, exact
// np fp32 refine (pairwise X/w2, ascending-d fma chain, strict-< tiebreak).
__global__ __launch_bounds__(NTH, 6) void vq_fused(
    const float* __restrict__ x, const float* __restrict__ w,
    const float* __restrict__ w2g, const uint4* __restrict__ wswz,
    float* __restrict__ out_q, float* __restrict__ out_enc,
    float* __restrict__ out_idx, double* __restrict__ partial) {

  __shared__ u64 candm[PXB][8];       // 4 KB: 512-bit candidate mask per pixel
  __shared__ float w2l[KC];           // 2 KB
  __shared__ float Xs[PXB];
  __shared__ int sidx[PXB];
  __shared__ float sredf[4];

  const int tid = threadIdx.x;
  const int lane = tid & 63;
  const int wv = tid >> 6;            // wave 0..3, each owns 16 pixels
  const int bix = blockIdx.x;
  const int b = bix >> 6;             // 64 blocks per image (4096/64)
  const int p0 = (bix & 63) * PXB;
  const float* xt = x + (size_t)b * (DD * HW) + p0;   // this block's x tile

  for (int i = tid; i < PXB * 8; i += NTH) ((u64*)candm)[i] = 0;
  w2l[tid] = w2g[tid]; w2l[tid + 256] = w2g[tid + 256];

  // ---- Xs: np-pairwise ||x||^2 from global x (one px per thread) ----
  if (tid < PXB) {
    const float* xp = xt + tid;
    float r0 = __fmul_rn(xp[0*HW], xp[0*HW]), r1 = __fmul_rn(xp[1*HW], xp[1*HW]),
          r2 = __fmul_rn(xp[2*HW], xp[2*HW]), r3 = __fmul_rn(xp[3*HW], xp[3*HW]),
          r4 = __fmul_rn(xp[4*HW], xp[4*HW]), r5 = __fmul_rn(xp[5*HW], xp[5*HW]),
          r6 = __fmul_rn(xp[6*HW], xp[6*HW]), r7 = __fmul_rn(xp[7*HW], xp[7*HW]);
    #pragma unroll
    for (int i = 8; i < DD; i += 8) {
      r0 = __fadd_rn(r0, __fmul_rn(xp[(size_t)(i+0)*HW], xp[(size_t)(i+0)*HW]));
      r1 = __fadd_rn(r1, __fmul_rn(xp[(size_t)(i+1)*HW], xp[(size_t)(i+1)*HW]));
      r2 = __fadd_rn(r2, __fmul_rn(xp[(size_t)(i+2)*HW], xp[(size_t)(i+2)*HW]));
      r3 = __fadd_rn(r3, __fmul_rn(xp[(size_t)(i+3)*HW], xp[(size_t)(i+3)*HW]));
      r4 = __fadd_rn(r4, __fmul_rn(xp[(size_t)(i+4)*HW], xp[(size_t)(i+4)*HW]));
      r5 = __fadd_rn(r5, __fmul_rn(xp[(size_t)(i+5)*HW], xp[(size_t)(i+5)*HW]));
      r6 = __fadd_rn(r6, __fmul_rn(xp[(size_t)(i+6)*HW], xp[(size_t)(i+6)*HW]));
      r7 = __fadd_rn(r7, __fmul_rn(xp[(size_t)(i+7)*HW], xp[(size_t)(i+7)*HW]));
    }
    Xs[tid] = __fadd_rn(__fadd_rn(__fadd_rn(r0, r1), __fadd_rn(r2, r3)),
                        __fadd_rn(__fadd_rn(r4, r5), __fadd_rn(r6, r7)));
  }

  // ---- A-frags from global x: A[m=lane&15][k=quad*8+j] of (-2x), bf16 ----
  const int am = lane & 15, aq = lane >> 4;
  const float* xa = xt + wv * 16 + am;
  short8 a0, a1;
  #pragma unroll
  for (int j = 0; j < 8; ++j) {
    a0[j] = (short)bf16_rne(-2.0f * xa[(size_t)(aq * 8 + j) * HW]);
    a1[j] = (short)bf16_rne(-2.0f * xa[(size_t)(32 + aq * 8 + j) * HW]);
  }

  __syncthreads();   // candm zero + w2l ready

  const short8* gw8 = (const short8*)wswz;
  const int cn = lane & 15;   // C-layout col (code within tile)

  // ---- pass 1: per-pixel min of screened S over 512 codes ----
  // C layout (m89-verified): col=lane&15, row=(lane>>4)*4+reg
  float m0 = FLT_MAX, m1 = FLT_MAX, m2 = FLT_MAX, m3 = FLT_MAX;
  for (int ct = 0; ct < 32; ++ct) {
    float wk2 = w2l[ct * 16 + cn];
    f32x4 acc = {wk2, wk2, wk2, wk2};
    acc = __builtin_amdgcn_mfma_f32_16x16x32_bf16(a0, gw8[ct * 128 + lane], acc, 0, 0, 0);
    acc = __builtin_amdgcn_mfma_f32_16x16x32_bf16(a1, gw8[ct * 128 + 64 + lane], acc, 0, 0, 0);
    m0 = fminf(m0, acc[0]); m1 = fminf(m1, acc[1]);
    m2 = fminf(m2, acc[2]); m3 = fminf(m3, acc[3]);
  }
  #pragma unroll
  for (int s = 1; s < 16; s <<= 1) {
    m0 = fminf(m0, __shfl_xor(m0, s));
    m1 = fminf(m1, __shfl_xor(m1, s));
    m2 = fminf(m2, __shfl_xor(m2, s));
    m3 = fminf(m3, __shfl_xor(m3, s));
  }
  const float t0 = m0 + MARGIN, t1 = m1 + MARGIN,
              t2 = m2 + MARGIN, t3 = m3 + MARGIN;

  // ---- pass 2: flag candidates into per-pixel bitmasks ----
  for (int ct = 0; ct < 32; ++ct) {
    float wk2 = w2l[ct * 16 + cn];
    f32x4 acc = {wk2, wk2, wk2, wk2};
    acc = __builtin_amdgcn_mfma_f32_16x16x32_bf16(a0, gw8[ct * 128 + lane], acc, 0, 0, 0);
    acc = __builtin_amdgcn_mfma_f32_16x16x32_bf16(a1, gw8[ct * 128 + 64 + lane], acc, 0, 0, 0);
    u64 bm0 = __ballot(acc[0] <= t0);
    u64 bm1 = __ballot(acc[1] <= t1);
    u64 bm2 = __ballot(acc[2] <= t2);
    u64 bm3 = __ballot(acc[3] <= t3);
    if (lane < 4) {   // lane r owns reg r; ballot bit (q*16+n) -> pixel q*4+r, code ct*16+n
      u64 mk = (lane == 0) ? bm0 : (lane == 1) ? bm1 : (lane == 2) ? bm2 : bm3;
      int word = ct >> 2, sh = (ct & 3) * 16;
      #pragma unroll
      for (int q = 0; q < 4; ++q) {
        u64 bits = (mk >> (q * 16)) & 0xFFFFull;
        if (bits) candm[wv * 16 + q * 4 + lane][word] |= bits << sh;
      }
    }
  }
  __syncthreads();

  // ---- refine: 4 threads per pixel, exact np fp32 dist over candidates ----
  {
    const int px = tid >> 2, part = tid & 3;
    const float X = Xs[px];
    const float* xr = xt + px;
    float bestd = FLT_MAX; int bk = 1 << 30;
    for (int wd = part * 2; wd < part * 2 + 2; ++wd) {
      u64 msk = candm[px][wd];
      while (msk) {
        int bit = __ffsll((unsigned long long)msk) - 1;
        msk &= msk - 1;
        int k = wd * 64 + bit;
        const float* wp = w + k * DD;
        float P = 0.f;                       // ascending-d fma chain (BLAS order)
        #pragma unroll
        for (int dc = 0; dc < 16; ++dc) {
          nfloat4 w4 = *(const nfloat4*)(wp + dc * 4);
          P = __fmaf_rn(xr[(size_t)(dc * 4 + 0) * HW], w4[0], P);
          P = __fmaf_rn(xr[(size_t)(dc * 4 + 1) * HW], w4[1], P);
          P = __fmaf_rn(xr[(size_t)(dc * 4 + 2) * HW], w4[2], P);
          P = __fmaf_rn(xr[(size_t)(dc * 4 + 3) * HW], w4[3], P);
        }
        float dist = __fsub_rn(__fadd_rn(X, w2l[k]), __fadd_rn(P, P));
        if (dist < bestd || (dist == bestd && k < bk)) { bestd = dist; bk = k; }
      }
    }
    float od = __shfl_down(bestd, 1); int ok = __shfl_down(bk, 1);
    if ((lane & 3) < 3 && (od < bestd || (od == bestd && ok < bk))) { bestd = od; bk = ok; }
    od = __shfl_down(bestd, 2); ok = __shfl_down(bk, 2);
    if ((lane & 3) < 2 && (od < bestd || (od == bestd && ok < bk))) { bestd = od; bk = ok; }
    if (part == 0) {
      sidx[px] = bk;
      out_idx[bix * PXB + px] = (float)bk;
    }
  }
  __syncthreads();

  // ---- quant (coalesced 256B rows) + loss ----
  float lsum = 0.f;
  float* qb = out_q + (size_t)b * (DD * HW) + p0;
  for (int i = tid; i < PXB * DD; i += NTH) {
    int d = i >> 6, pp = i & 63;
    float qv = w[sidx[pp] * DD + d];      // L1/L2-resident gather
    float dv = qv - xt[(size_t)d * HW + pp];
    lsum = __fmaf_rn(dv, dv, lsum);
    __builtin_nontemporal_store(qv, qb + (size_t)d * HW + pp);
  }
  #pragma unroll
  for (int off = 32; off > 0; off >>= 1) lsum += __shfl_down(lsum, off);
  if (lane == 0) sredf[wv] = lsum;
  __syncthreads();
  if (tid == 0)
    partial[bix] = (double)sredf[0] + (double)sredf[1]
                 + (double)sredf[2] + (double)sredf[3];

  // ---- one-hot enc (base ≡ 1 mod 4 floats: 3-head, aligned body, 1-tail) ----
  float* basep = out_enc + (size_t)bix * (PXB * KC);
  for (int t = tid; t < 8191; t += NTH) {
    int u = 3 + 4 * t;
    nfloat4 v;
    #pragma unroll
    for (int j = 0; j < 4; ++j) {
      int e = u + j;
      v[j] = (sidx[e >> 9] == (e & 511)) ? 1.0f : 0.0f;
    }
    __builtin_nontemporal_store(v, (nfloat4*)(basep + u));
  }
  if (tid < 3) basep[tid] = (sidx[0] == tid) ? 1.0f : 0.0f;
  else if (tid == 3) basep[PXB * KC - 1] = (sidx[PXB - 1] == 511) ? 1.0f : 0.0f;
}

// --- epilogue: loss = vq + commit = 2 * mean((q - x)^2) ---
__global__ void finish_kernel(const double* __restrict__ partial,
                              float* __restrict__ out) {
  int t = threadIdx.x;   // 256 threads, 2048 partials
  double s = 0.0;
  #pragma unroll
  for (int i = 0; i < 8; ++i) s += partial[t + 256 * i];
  #pragma unroll
  for (int off = 32; off > 0; off >>= 1) s += __shfl_down(s, off);
  __shared__ double sr[4];
  if ((t & 63) == 0) sr[t >> 6] = s;
  __syncthreads();
  if (t == 0)
    out[0] = (float)(2.0 * (sr[0] + sr[1] + sr[2] + sr[3]) / (double)QSIZE);
}

extern "C" void kernel_launch(void* const* d_in, const int* in_sizes, int n_in,
                              void* d_out, int out_size, void* d_ws, size_t ws_size,
                              hipStream_t stream) {
  const float* x = (const float*)d_in[0];   // [32,64,64,64] f32 NCHW
  const float* w = (const float*)d_in[1];   // [512,64] f32
  float* out = (float*)d_out;
  float* out_q = out + 1;
  float* out_enc = out_q + QSIZE;
  float* out_idx = out_enc + (size_t)NPIX * KC;

  // d_ws layout: partial[2048] @0 (16 KB) | w2g[512] @16384 | wswz[4096] @18432
  double* partial = (double*)d_ws;
  float* w2g = (float*)((char*)d_ws + 16384);
  uint4* wswz = (uint4*)((char*)d_ws + 18432);

  prep<<<4, 1024, 0, stream>>>(w, w2g, wswz);
  vq_fused<<<NBLK, NTH, 0, stream>>>(x, w, w2g, wswz, out_q, out_enc, out_idx, partial);
  finish_kernel<<<1, 256, 0, stream>>>(partial, out);
}

// Round 11
// 382.194 us; speedup vs baseline: 1.1249x; 1.1249x over previous
//
#include <hip/hip_runtime.h>
#include <cfloat>

#define KC 512        // codes
#define DD 64         // dim
#define HW 4096       // 64*64
#define NPIX 131072   // 32*64*64
#define QSIZE 8388608 // 32*64*64*64
#define PXB 128       // pixels per block
#define NBLK (NPIX / PXB)  // 1024
#define NTH 512       // 8 waves
#define MARGIN 4.0e-3f  // >6x worst-case screen-vs-np error bound

typedef short short8 __attribute__((ext_vector_type(8)));   // 8 bf16 MFMA operand
typedef float f32x4 __attribute__((ext_vector_type(4)));
typedef float nfloat4 __attribute__((ext_vector_type(4)));
typedef unsigned long long u64;

__device__ __forceinline__ unsigned short bf16_rne(float f) {
    unsigned int u = __float_as_uint(f);
    u += 0x7FFFu + ((u >> 16) & 1u);
    return (unsigned short)(u >> 16);
}

// --- prep (once per launch, validated R10): swizzled bf16 B-frag codebook
// (64 KB) + np-pairwise w2. Slot s=(ct*2+kc)*64+ln holds
// w[ct*16+(ln&15)][kc*32+(ln>>4)*8 .. +8) as bf16x8.
__global__ __launch_bounds__(1024) void prep(
    const float* __restrict__ w, float* __restrict__ w2g,
    uint4* __restrict__ wswz) {
  const int gt = blockIdx.x * 1024 + threadIdx.x;   // 0..4095
  {
    int ct = gt >> 7, kc = (gt >> 6) & 1, ln = gt & 63;
    int n = ln & 15, q = ln >> 4;
    const float* wp = w + (ct * 16 + n) * DD + kc * 32 + q * 8;
    nfloat4 f0 = *(const nfloat4*)(wp);
    nfloat4 f1 = *(const nfloat4*)(wp + 4);
    uint4 u;
    u.x = (unsigned)bf16_rne(f0[0]) | ((unsigned)bf16_rne(f0[1]) << 16);
    u.y = (unsigned)bf16_rne(f0[2]) | ((unsigned)bf16_rne(f0[3]) << 16);
    u.z = (unsigned)bf16_rne(f1[0]) | ((unsigned)bf16_rne(f1[1]) << 16);
    u.w = (unsigned)bf16_rne(f1[2]) | ((unsigned)bf16_rne(f1[3]) << 16);
    wswz[gt] = u;
  }
  if (gt < KC) {      // w2g[k]: numpy-pairwise fp32 sum of squares
    const float* wk = w + gt * DD;
    float r0 = __fmul_rn(wk[0], wk[0]), r1 = __fmul_rn(wk[1], wk[1]),
          r2 = __fmul_rn(wk[2], wk[2]), r3 = __fmul_rn(wk[3], wk[3]),
          r4 = __fmul_rn(wk[4], wk[4]), r5 = __fmul_rn(wk[5], wk[5]),
          r6 = __fmul_rn(wk[6], wk[6]), r7 = __fmul_rn(wk[7], wk[7]);
    #pragma unroll
    for (int i = 8; i < DD; i += 8) {
      r0 = __fadd_rn(r0, __fmul_rn(wk[i+0], wk[i+0]));
      r1 = __fadd_rn(r1, __fmul_rn(wk[i+1], wk[i+1]));
      r2 = __fadd_rn(r2, __fmul_rn(wk[i+2], wk[i+2]));
      r3 = __fadd_rn(r3, __fmul_rn(wk[i+3], wk[i+3]));
      r4 = __fadd_rn(r4, __fmul_rn(wk[i+4], wk[i+4]));
      r5 = __fadd_rn(r5, __fmul_rn(wk[i+5], wk[i+5]));
      r6 = __fadd_rn(r6, __fmul_rn(wk[i+6], wk[i+6]));
      r7 = __fadd_rn(r7, __fmul_rn(wk[i+7], wk[i+7]));
    }
    w2g[gt] = __fadd_rn(__fadd_rn(__fadd_rn(r0, r1), __fadd_rn(r2, r3)),
                        __fadd_rn(__fadd_rn(r4, r5), __fadd_rn(r6, r7)));
  }
}

// --- main: R9 structure (391 µs anchor — best) with staging simplified to
// plain copies of the prep-built arrays. 128 px / 512 thr / ~75 KB LDS ->
// 2 blocks/CU so enc-store phase overlaps co-resident block's compute.
__global__ __launch_bounds__(NTH, 4) void vq_fused(
    const float* __restrict__ x, const float* __restrict__ w,
    const float* __restrict__ w2g, const uint4* __restrict__ wswz,
    float* __restrict__ out_q, float* __restrict__ out_enc,
    float* __restrict__ out_idx, double* __restrict__ partial) {

  __shared__ uint4 wlds[4096];        // 64 KB: B-frags, slot=(ct*2+kc)*64+lane
  __shared__ float w2s[KC];           // 2 KB: np-exact ||w_k||^2
  __shared__ u64 candm[PXB][8];       // 8 KB: 512-bit candidate mask per pixel
  __shared__ float Xs[PXB];           // np-exact ||x||^2 per pixel
  __shared__ int sidx[PXB];
  __shared__ float sredf[8];

  const int tid = threadIdx.x;
  const int lane = tid & 63;
  const int wv = tid >> 6;            // wave 0..7, each owns 16 pixels
  const int bix = blockIdx.x;
  const int b = bix >> 5;             // 32 blocks per image (4096/128)
  const int p0 = (bix & 31) * PXB;
  const float* xt = x + (size_t)b * (DD * HW) + p0;   // this block's x tile

  // ---- stage prebuilt codebook: pure coalesced copies, no math ----
  #pragma unroll
  for (int s = 0; s < 8; ++s) wlds[tid + s * NTH] = wswz[tid + s * NTH];
  w2s[tid] = w2g[tid];
  if (tid < KC - NTH) w2s[tid + NTH] = w2g[tid + NTH];
  for (int i = tid; i < PXB * 8; i += NTH) ((u64*)candm)[i] = 0;

  // ---- Xs: np-pairwise ||x||^2 from global x (one px per thread) ----
  if (tid < PXB) {
    const float* xp = xt + tid;
    float r0 = __fmul_rn(xp[0*HW], xp[0*HW]), r1 = __fmul_rn(xp[1*HW], xp[1*HW]),
          r2 = __fmul_rn(xp[2*HW], xp[2*HW]), r3 = __fmul_rn(xp[3*HW], xp[3*HW]),
          r4 = __fmul_rn(xp[4*HW], xp[4*HW]), r5 = __fmul_rn(xp[5*HW], xp[5*HW]),
          r6 = __fmul_rn(xp[6*HW], xp[6*HW]), r7 = __fmul_rn(xp[7*HW], xp[7*HW]);
    #pragma unroll
    for (int i = 8; i < DD; i += 8) {
      r0 = __fadd_rn(r0, __fmul_rn(xp[(size_t)(i+0)*HW], xp[(size_t)(i+0)*HW]));
      r1 = __fadd_rn(r1, __fmul_rn(xp[(size_t)(i+1)*HW], xp[(size_t)(i+1)*HW]));
      r2 = __fadd_rn(r2, __fmul_rn(xp[(size_t)(i+2)*HW], xp[(size_t)(i+2)*HW]));
      r3 = __fadd_rn(r3, __fmul_rn(xp[(size_t)(i+3)*HW], xp[(size_t)(i+3)*HW]));
      r4 = __fadd_rn(r4, __fmul_rn(xp[(size_t)(i+4)*HW], xp[(size_t)(i+4)*HW]));
      r5 = __fadd_rn(r5, __fmul_rn(xp[(size_t)(i+5)*HW], xp[(size_t)(i+5)*HW]));
      r6 = __fadd_rn(r6, __fmul_rn(xp[(size_t)(i+6)*HW], xp[(size_t)(i+6)*HW]));
      r7 = __fadd_rn(r7, __fmul_rn(xp[(size_t)(i+7)*HW], xp[(size_t)(i+7)*HW]));
    }
    Xs[tid] = __fadd_rn(__fadd_rn(__fadd_rn(r0, r1), __fadd_rn(r2, r3)),
                        __fadd_rn(__fadd_rn(r4, r5), __fadd_rn(r6, r7)));
  }

  // ---- A-frags from global x: A[m=lane&15][k=quad*8+j] of (-2x), bf16 ----
  const int am = lane & 15, aq = lane >> 4;
  const float* xa = xt + wv * 16 + am;
  short8 a0, a1;
  #pragma unroll
  for (int j = 0; j < 8; ++j) {
    a0[j] = (short)bf16_rne(-2.0f * xa[(size_t)(aq * 8 + j) * HW]);
    a1[j] = (short)bf16_rne(-2.0f * xa[(size_t)(32 + aq * 8 + j) * HW]);
  }

  __syncthreads();   // wlds + w2s + candm ready

  const short8* wl8 = (const short8*)wlds;
  const int cn = lane & 15;   // C-layout col (code within tile)

  // ---- pass 1: per-pixel min of screened S over 512 codes ----
  // C layout (m89-verified): col=lane&15, row=(lane>>4)*4+reg
  float m0 = FLT_MAX, m1 = FLT_MAX, m2 = FLT_MAX, m3 = FLT_MAX;
  for (int ct = 0; ct < 32; ++ct) {
    float wk2 = w2s[ct * 16 + cn];
    f32x4 acc = {wk2, wk2, wk2, wk2};
    acc = __builtin_amdgcn_mfma_f32_16x16x32_bf16(a0, wl8[ct * 128 + lane], acc, 0, 0, 0);
    acc = __builtin_amdgcn_mfma_f32_16x16x32_bf16(a1, wl8[ct * 128 + 64 + lane], acc, 0, 0, 0);
    m0 = fminf(m0, acc[0]); m1 = fminf(m1, acc[1]);
    m2 = fminf(m2, acc[2]); m3 = fminf(m3, acc[3]);
  }
  #pragma unroll
  for (int s = 1; s < 16; s <<= 1) {
    m0 = fminf(m0, __shfl_xor(m0, s));
    m1 = fminf(m1, __shfl_xor(m1, s));
    m2 = fminf(m2, __shfl_xor(m2, s));
    m3 = fminf(m3, __shfl_xor(m3, s));
  }
  const float t0 = m0 + MARGIN, t1 = m1 + MARGIN,
              t2 = m2 + MARGIN, t3 = m3 + MARGIN;

  // ---- pass 2: flag candidates into per-pixel bitmasks ----
  for (int ct = 0; ct < 32; ++ct) {
    float wk2 = w2s[ct * 16 + cn];
    f32x4 acc = {wk2, wk2, wk2, wk2};
    acc = __builtin_amdgcn_mfma_f32_16x16x32_bf16(a0, wl8[ct * 128 + lane], acc, 0, 0, 0);
    acc = __builtin_amdgcn_mfma_f32_16x16x32_bf16(a1, wl8[ct * 128 + 64 + lane], acc, 0, 0, 0);
    u64 bm0 = __ballot(acc[0] <= t0);
    u64 bm1 = __ballot(acc[1] <= t1);
    u64 bm2 = __ballot(acc[2] <= t2);
    u64 bm3 = __ballot(acc[3] <= t3);
    if (lane < 4) {   // lane r owns reg r; ballot bit (q*16+n) -> pixel q*4+r, code ct*16+n
      u64 mk = (lane == 0) ? bm0 : (lane == 1) ? bm1 : (lane == 2) ? bm2 : bm3;
      int word = ct >> 2, sh = (ct & 3) * 16;
      #pragma unroll
      for (int q = 0; q < 4; ++q) {
        u64 bits = (mk >> (q * 16)) & 0xFFFFull;
        if (bits) candm[wv * 16 + q * 4 + lane][word] |= bits << sh;
      }
    }
  }
  __syncthreads();

  // ---- refine: 4 threads per pixel, exact np fp32 dist over candidates ----
  {
    const int px = tid >> 2, part = tid & 3;
    const float X = Xs[px];
    const float* xr = xt + px;
    float bestd = FLT_MAX; int bk = 1 << 30;
    for (int wd = part * 2; wd < part * 2 + 2; ++wd) {
      u64 msk = candm[px][wd];
      while (msk) {
        int bit = __ffsll((unsigned long long)msk) - 1;
        msk &= msk - 1;
        int k = wd * 64 + bit;
        const float* wp = w + k * DD;
        float P = 0.f;                       // ascending-d fma chain (BLAS order)
        #pragma unroll
        for (int dc = 0; dc < 16; ++dc) {
          nfloat4 w4 = *(const nfloat4*)(wp + dc * 4);
          P = __fmaf_rn(xr[(size_t)(dc * 4 + 0) * HW], w4[0], P);
          P = __fmaf_rn(xr[(size_t)(dc * 4 + 1) * HW], w4[1], P);
          P = __fmaf_rn(xr[(size_t)(dc * 4 + 2) * HW], w4[2], P);
          P = __fmaf_rn(xr[(size_t)(dc * 4 + 3) * HW], w4[3], P);
        }
        float dist = __fsub_rn(__fadd_rn(X, w2s[k]), __fadd_rn(P, P));
        if (dist < bestd || (dist == bestd && k < bk)) { bestd = dist; bk = k; }
      }
    }
    // merge the 4 parts (tie -> smaller k, matching np.argmin first-index)
    float od = __shfl_down(bestd, 1); int ok = __shfl_down(bk, 1);
    if ((lane & 3) < 3 && (od < bestd || (od == bestd && ok < bk))) { bestd = od; bk = ok; }
    od = __shfl_down(bestd, 2); ok = __shfl_down(bk, 2);
    if ((lane & 3) < 2 && (od < bestd || (od == bestd && ok < bk))) { bestd = od; bk = ok; }
    if (part == 0) {
      sidx[px] = bk;
      out_idx[bix * PXB + px] = (float)bk;
    }
  }
  __syncthreads();

  // ---- quant (coalesced 256B rows) + loss ----
  float lsum = 0.f;
  float* qb = out_q + (size_t)b * (DD * HW) + p0;
  for (int i = tid; i < PXB * DD; i += NTH) {
    int d = i >> 7, pp = i & 127;
    float qv = w[sidx[pp] * DD + d];      // L1/L2-resident gather
    float dv = qv - xt[(size_t)d * HW + pp];
    lsum = __fmaf_rn(dv, dv, lsum);
    __builtin_nontemporal_store(qv, qb + (size_t)d * HW + pp);
  }
  #pragma unroll
  for (int off = 32; off > 0; off >>= 1) lsum += __shfl_down(lsum, off);
  if (lane == 0) sredf[wv] = lsum;
  __syncthreads();
  if (tid == 0) {
    double t = 0.0;
    #pragma unroll
    for (int i = 0; i < 8; ++i) t += (double)sredf[i];
    partial[bix] = t;
  }

  // ---- one-hot enc (base ≡ 1 mod 4 floats: 3-head, aligned body, 1-tail) ----
  float* basep = out_enc + (size_t)bix * (PXB * KC);
  for (int t = tid; t < 16383; t += NTH) {
    int u = 3 + 4 * t;
    nfloat4 v;
    #pragma unroll
    for (int j = 0; j < 4; ++j) {
      int e = u + j;
      v[j] = (sidx[e >> 9] == (e & 511)) ? 1.0f : 0.0f;
    }
    __builtin_nontemporal_store(v, (nfloat4*)(basep + u));
  }
  if (tid < 3) basep[tid] = (sidx[0] == tid) ? 1.0f : 0.0f;
  else if (tid == 3) basep[PXB * KC - 1] = (sidx[127] == 511) ? 1.0f : 0.0f;
}

// --- epilogue: loss = vq + commit = 2 * mean((q - x)^2) ---
__global__ void finish_kernel(const double* __restrict__ partial,
                              float* __restrict__ out) {
  int t = threadIdx.x;   // 256 threads, 1024 partials
  double s = partial[t] + partial[t + 256] + partial[t + 512] + partial[t + 768];
  #pragma unroll
  for (int off = 32; off > 0; off >>= 1) s += __shfl_down(s, off);
  __shared__ double sr[4];
  if ((t & 63) == 0) sr[t >> 6] = s;
  __syncthreads();
  if (t == 0)
    out[0] = (float)(2.0 * (sr[0] + sr[1] + sr[2] + sr[3]) / (double)QSIZE);
}

extern "C" void kernel_launch(void* const* d_in, const int* in_sizes, int n_in,
                              void* d_out, int out_size, void* d_ws, size_t ws_size,
                              hipStream_t stream) {
  const float* x = (const float*)d_in[0];   // [32,64,64,64] f32 NCHW
  const float* w = (const float*)d_in[1];   // [512,64] f32
  float* out = (float*)d_out;
  float* out_q = out + 1;
  float* out_enc = out_q + QSIZE;
  float* out_idx = out_enc + (size_t)NPIX * KC;

  // d_ws layout: partial[1024] @0 (8 KB) | w2g[512] @8192 | wswz[4096] @16384
  double* partial = (double*)d_ws;
  float* w2g = (float*)((char*)d_ws + 8192);
  uint4* wswz = (uint4*)((char*)d_ws + 16384);

  prep<<<4, 1024, 0, stream>>>(w, w2g, wswz);
  vq_fused<<<NBLK, NTH, 0, stream>>>(x, w, w2g, wswz, out_q, out_enc, out_idx, partial);
  finish_kernel<<<1, 256, 0, stream>>>(partial, out);
}